// Round 7
// baseline (242.121 us; speedup 1.0000x reference)
//
#include <hip/hip_runtime.h>

typedef __attribute__((ext_vector_type(4))) float f32x4;
typedef __attribute__((ext_vector_type(8))) __bf16 bf16x8;
typedef __attribute__((ext_vector_type(4))) __bf16 bf16x4;

#define QSCALE (0.125f * 1.4426950408889634f)   // d^-0.5 * log2(e), folded into q

__device__ __forceinline__ void load_lds16(const void* g, void* l) {
  __builtin_amdgcn_global_load_lds(
      (const __attribute__((address_space(1))) unsigned int*)g,
      (__attribute__((address_space(3))) unsigned int*)l, 16, 0, 0);
}

__device__ __forceinline__ f32x4 mfma16(bf16x8 a, bf16x8 b, f32x4 c) {
  return __builtin_amdgcn_mfma_f32_16x16x32_bf16(a, b, c, 0, 0, 0);
}

__device__ __forceinline__ bf16x8 cat44(bf16x4 a, bf16x4 b) {
  return __builtin_shufflevector(a, b, 0, 1, 2, 3, 4, 5, 6, 7);
}

// ---------------- prep kernels ----------------

__global__ __launch_bounds__(256) void k_cast_x(const float* __restrict__ in,
                                                __bf16* __restrict__ out) {
  int i = blockIdx.x * 256 + threadIdx.x;           // 8 floats per thread
  const f32x4* in4 = (const f32x4*)in;
  f32x4 a = in4[i * 2], b = in4[i * 2 + 1];
  bf16x8 o;
  o[0] = (__bf16)a[0]; o[1] = (__bf16)a[1]; o[2] = (__bf16)a[2]; o[3] = (__bf16)a[3];
  o[4] = (__bf16)b[0]; o[5] = (__bf16)b[1]; o[6] = (__bf16)b[2]; o[7] = (__bf16)b[3];
  *(bf16x8*)(out + (size_t)i * 8) = o;
}

// in [R][C] f32  ->  out [C][R] bf16
__global__ void k_transpose_cast(const float* __restrict__ in, __bf16* __restrict__ out,
                                 int R, int C) {
  __shared__ float t[32][33];
  int c0 = blockIdx.x * 32, r0 = blockIdx.y * 32;
  int tx = threadIdx.x, ty = threadIdx.y;           // 32 x 8
#pragma unroll
  for (int j = 0; j < 32; j += 8)
    t[ty + j][tx] = in[(size_t)(r0 + ty + j) * C + c0 + tx];
  __syncthreads();
#pragma unroll
  for (int j = 0; j < 32; j += 8)
    out[(size_t)(c0 + ty + j) * R + r0 + tx] = (__bf16)t[tx][ty + j];
}

// -------- GEMM core, double-buffered (128x128 tile, BK=32, B^T input) --------
// smem layout: As0 [0,8K) As1 [8K,16K) Bs0 [16K,24K) Bs1 [24K,32K)

template <int NT>
__device__ __forceinline__ void gemm_core(const char* aB, const char* bB,
                                          char* smem, int tid, int l,
                                          int wr, int wc, f32x4 (&acc)[4][4]) {
  auto stage = [&](int buf, int kt) {
#pragma unroll
    for (int is = 0; is < 2; ++is) {
      int o = is * 4096 + tid * 16;
      int row = o >> 6, cb = (o >> 4) & 3;
      int src = row * 1536 + (((cb ^ row) & 3) << 4) + kt * 64;
      load_lds16(aB + src, smem + buf * 8192 + o);
      load_lds16(bB + src, smem + 16384 + buf * 8192 + o);
    }
  };
  stage(0, 0);
#pragma unroll 2
  for (int kt = 0; kt < NT; ++kt) {
    int cur = kt & 1;
    __syncthreads();
    if (kt + 1 < NT) stage(cur ^ 1, kt + 1);
    const __bf16* As = (const __bf16*)(smem + cur * 8192);
    const __bf16* Bs = (const __bf16*)(smem + 16384 + cur * 8192);
    bf16x8 af[4], bfr[4];
#pragma unroll
    for (int mf = 0; mf < 4; ++mf) {
      int row = wr * 64 + mf * 16 + (l & 15);
      af[mf] = *(const bf16x8*)&As[row * 32 + ((((l >> 4) ^ row) & 3) << 3)];
    }
#pragma unroll
    for (int nf = 0; nf < 4; ++nf) {
      int row = wc * 64 + nf * 16 + (l & 15);
      bfr[nf] = *(const bf16x8*)&Bs[row * 32 + ((((l >> 4) ^ row) & 3) << 3)];
    }
    __builtin_amdgcn_s_setprio(1);
#pragma unroll
    for (int mf = 0; mf < 4; ++mf)
#pragma unroll
      for (int nf = 0; nf < 4; ++nf)
        acc[mf][nf] = mfma16(af[mf], bfr[nf], acc[mf][nf]);
    __builtin_amdgcn_s_setprio(0);
  }
  __syncthreads();
}

// ---------------- QKV GEMM -> q,k,v with coalesced LDS-transposed epilogues ----------------

__global__ __launch_bounds__(256, 3) void k_qkv(const __bf16* __restrict__ A,
                                                const __bf16* __restrict__ BT,
                                                __bf16* __restrict__ qb,
                                                __bf16* __restrict__ kb,
                                                __bf16* __restrict__ vT) {
  __shared__ __align__(16) char smem[32768];
  int tid = threadIdx.x, l = tid & 63, w = tid >> 6, wr = w >> 1, wc = w & 1;
  int g = l >> 4, c = l & 15;
  int m0 = blockIdx.y * 128, n0 = blockIdx.x * 128;
  f32x4 acc[4][4] = {};
  gemm_core<24>((const char*)(A + (size_t)m0 * 768), (const char*)(BT + (size_t)n0 * 768),
                smem, tid, l, wr, wc, acc);
  int b = m0 >> 11, m0l = m0 & 2047;
  int sel = n0 / 768;
  int rem = n0 - sel * 768;

  if (sel == 2) {
    // build [dd 128][tok 128] bf16 tile (packed b64 writes), then coalesced vT rows
#pragma unroll
    for (int mf = 0; mf < 4; ++mf) {
      int tokb = wr * 64 + mf * 16 + 4 * g;
      int gr = tokb >> 3, low = (g & 1) << 3;
#pragma unroll
      for (int nf = 0; nf < 4; ++nf) {
        int dd = wc * 64 + nf * 16 + c;
        bf16x4 pk;
        pk[0] = (__bf16)acc[mf][nf][0]; pk[1] = (__bf16)acc[mf][nf][1];
        pk[2] = (__bf16)acc[mf][nf][2]; pk[3] = (__bf16)acc[mf][nf][3];
        *(bf16x4*)(smem + dd * 256 + (((gr ^ (dd & 15)) & 15) << 4) + low) = pk;
      }
    }
    __syncthreads();
#pragma unroll
    for (int p = 0; p < 8; ++p) {
      int idx = p * 256 + tid;
      int dd = idx >> 4, t8 = idx & 15;
      bf16x8 v = *(const bf16x8*)(smem + dd * 256 + (((t8 ^ (dd & 15)) & 15) << 4));
      int colg = rem + dd;
      int h = colg >> 6, d = colg & 63;
      *(bf16x8*)(vT + (((size_t)(b * 12 + h)) * 64 + d) * 2048 + m0l + t8 * 8) = v;
    }
  } else {
    // build [tok 128][col 128] bf16 tile, then coalesced q/k rows
    float qs = (sel == 0) ? QSCALE : 1.0f;
#pragma unroll
    for (int mf = 0; mf < 4; ++mf)
#pragma unroll
      for (int nf = 0; nf < 4; ++nf) {
        int col = wc * 64 + nf * 16 + c;
        int grc = col >> 3, lowc = (col & 7) << 1;
#pragma unroll
        for (int r = 0; r < 4; ++r) {
          int tok = wr * 64 + mf * 16 + 4 * g + r;
          *(__bf16*)(smem + tok * 256 + (((grc ^ (tok & 15)) & 15) << 4) + lowc) =
              (__bf16)(acc[mf][nf][r] * qs);
        }
      }
    __syncthreads();
    __bf16* dst0 = (sel == 0) ? qb : kb;
#pragma unroll
    for (int p = 0; p < 8; ++p) {
      int idx = p * 256 + tid;
      int tok = idx >> 4, hh = (idx >> 3) & 1, d8 = idx & 7;
      int gr = hh * 8 + d8;
      bf16x8 v = *(const bf16x8*)(smem + tok * 256 + (((gr ^ (tok & 15)) & 15) << 4));
      int h = (rem >> 6) + hh;
      *(bf16x8*)(dst0 + (((size_t)(b * 12 + h)) * 2048 + m0l + tok) * 64 + d8 * 8) = v;
    }
  }
}

// ------- flash attention: 512 threads / 8 waves, QBLK=256, KV-split=4 -------
// grid = 8 qt x 24 bh x 4 sp = 768 = exactly 3 blocks/CU -> ONE round, no tail,
// 6 waves/SIMD steady. smem 32K: K0 [0,8K) K1 [8,16K) V0 [16,24K) V1 [24,32K);
// Q (256 x 128B = 32K) staged through the same buffer first.
// launch_bounds(512,6): VGPR cap 85 (body uses ~64, no spill).

__global__ __launch_bounds__(512, 6) void k_attn(const __bf16* __restrict__ qb,
                                                 const __bf16* __restrict__ kb,
                                                 const __bf16* __restrict__ vT,
                                                 __bf16* __restrict__ Op01,
                                                 __bf16* __restrict__ Op23,
                                                 float* __restrict__ lpart) {
  __shared__ __align__(16) char smem[32768];
  int tid = threadIdx.x, l = tid & 63, w = tid >> 6;   // w = 0..7
  int g = l >> 4, c = l & 15;
  // XCD-aware decode: 768 blocks = 8 XCDs x 96; same (bh,sp) stays on one XCD
  int phys = blockIdx.x;
  int lid = (phys & 7) * 96 + (phys >> 3);
  int qt = lid & 7;               // 0..7, 256 q-rows each
  int bhsp = lid >> 3;            // 0..95
  int bh = bhsp % 24, sp = bhsp / 24;   // sp 0..3, 512 keys each

  const char* qbase  = (const char*)qb + ((size_t)bh * 2048 + qt * 256) * 128;
  const char* kbase0 = (const char*)kb + (size_t)bh * 262144 + (size_t)sp * 65536;
  const char* vbase0 = (const char*)vT + (size_t)bh * 262144 + sp * 1024;

  // stage Q tile [256 q][64 d] (32KB) into smem, lift to registers
#pragma unroll
  for (int is = 0; is < 4; ++is) {
    int o = is * 8192 + tid * 16;
    int row = o >> 7, cb = (o >> 4) & 7;
    load_lds16(qbase + row * 128 + (((cb ^ row) & 7) << 4), smem + o);
  }
  __syncthreads();
  bf16x8 qf[2][2];
#pragma unroll
  for (int qi = 0; qi < 2; ++qi)
#pragma unroll
    for (int ks = 0; ks < 2; ++ks) {
      int q = w * 32 + qi * 16 + c;
      int gg = ks * 4 + g;
      qf[qi][ks] = *(const bf16x8*)(smem + q * 128 + (((gg ^ q) & 7) << 4));
    }
  __syncthreads();

  auto stageKV = [&](int buf, int t) {         // 8KB K + 8KB V, 1 load each per lane
    const char* kbase = kbase0 + t * 8192;
    const char* vbase = vbase0 + t * 128;
    int o = tid * 16;
    int r = o >> 7, cb = (o >> 4) & 7;
    load_lds16(kbase + r * 128 + (((cb ^ r) & 7) << 4), smem + buf * 8192 + o);
    load_lds16(vbase + (size_t)r * 4096 + (((cb ^ r) & 7) << 4),
               smem + 16384 + buf * 8192 + o);
  };

  float lacc[2] = {0.f, 0.f};
  f32x4 accO[2][4] = {};

  stageKV(0, 0);
#pragma unroll 2
  for (int t = 0; t < 8; ++t) {
    int cur = t & 1;
    __syncthreads();                           // drains stage(t) issued last iter
    if (t + 1 < 8) stageKV(cur ^ 1, t + 1);
    const char* KsB = smem + cur * 8192;
    const char* VsB = smem + 16384 + cur * 8192;

    // S^T = K @ Q^T (zero-seeded; scores stay in log2 domain via QSCALE)
    f32x4 s[4][2];
#pragma unroll
    for (int kf = 0; kf < 4; ++kf) {
      s[kf][0] = f32x4{0.f, 0.f, 0.f, 0.f};
      s[kf][1] = f32x4{0.f, 0.f, 0.f, 0.f};
    }
    __builtin_amdgcn_s_setprio(1);
#pragma unroll
    for (int ks = 0; ks < 2; ++ks) {
#pragma unroll
      for (int kf = 0; kf < 4; ++kf) {
        int key = kf * 16 + c;
        int gg = ks * 4 + g;
        bf16x8 kfr = *(const bf16x8*)(KsB + key * 128 + (((gg ^ key) & 7) << 4));
        s[kf][0] = mfma16(kfr, qf[0][ks], s[kf][0]);
        s[kf][1] = mfma16(kfr, qf[1][ks], s[kf][1]);
      }
    }
    __builtin_amdgcn_s_setprio(0);

    // p = exp2(s) via raw v_exp_f32; per-lane partial denominator
#pragma unroll
    for (int kf = 0; kf < 4; ++kf)
#pragma unroll
      for (int qi = 0; qi < 2; ++qi)
#pragma unroll
        for (int r = 0; r < 4; ++r) {
          float p = __builtin_amdgcn_exp2f(s[kf][qi][r]);
          s[kf][qi][r] = p;
          lacc[qi] += p;
        }

    // post-softmax task mask: q<4, key<4, off-diagonal -> 0 (numerator only)
    if (sp == 0 && qt == 0 && t == 0 && w == 0 && g == 0 && c < 4) {
#pragma unroll
      for (int r = 0; r < 4; ++r)
        if (r != c) s[0][0][r] = 0.f;
    }

    // pack P to bf16: pkv[qi][kf] = keys {16*kf + 4g + 0..3} for q-col c
    bf16x4 pkv[2][4];
#pragma unroll
    for (int qi = 0; qi < 2; ++qi)
#pragma unroll
      for (int kf = 0; kf < 4; ++kf) {
        bf16x4 pk;
        pk[0] = (__bf16)s[kf][qi][0]; pk[1] = (__bf16)s[kf][qi][1];
        pk[2] = (__bf16)s[kf][qi][2]; pk[3] = (__bf16)s[kf][qi][3];
        pkv[qi][kf] = pk;
      }

    // PV permuted-k: call ks covers keys {32ks+4g+r} u {32ks+16+4g+r}
    __builtin_amdgcn_s_setprio(1);
#pragma unroll
    for (int ks = 0; ks < 2; ++ks) {
      bf16x8 pa0 = cat44(pkv[0][2 * ks], pkv[0][2 * ks + 1]);
      bf16x8 pa1 = cat44(pkv[1][2 * ks], pkv[1][2 * ks + 1]);
      int low = (g & 1) << 3;
      int vc0 = ks * 4 + (g >> 1);
#pragma unroll
      for (int df = 0; df < 4; ++df) {
        int dd = df * 16 + c;
        const char* vrow = VsB + dd * 128;
        bf16x4 v0 = *(const bf16x4*)(vrow + (((vc0 ^ dd) & 7) << 4) + low);
        bf16x4 v1 = *(const bf16x4*)(vrow + ((((vc0 + 2) ^ dd) & 7) << 4) + low);
        bf16x8 vb = cat44(v0, v1);
        accO[0][df] = mfma16(pa0, vb, accO[0][df]);
        accO[1][df] = mfma16(pa1, vb, accO[1][df]);
      }
    }
    __builtin_amdgcn_s_setprio(0);
  }
  __syncthreads();

  // l reduction + store
  size_t pbase = ((size_t)(sp & 1) * 24 + bh) * 2048 + qt * 256;
  __bf16* Obase = (sp < 2) ? Op01 : Op23;
  float lfull[2];
#pragma unroll
  for (int qi = 0; qi < 2; ++qi) {
    float rr = lacc[qi];
    rr += __shfl_xor(rr, 16, 64);
    rr += __shfl_xor(rr, 32, 64);
    lfull[qi] = rr;
  }
  if (g == 0) {
    size_t lb = ((size_t)sp * 24 + bh) * 2048 + qt * 256;
#pragma unroll
    for (int qi = 0; qi < 2; ++qi)
      lpart[lb + w * 32 + qi * 16 + c] = lfull[qi];
  }

  // epilogue: per-wave [16][64] f32 transpose (4KB), 2 passes -> coalesced bf16x8 stores
  char* ep = smem + w * 4096;
#pragma unroll
  for (int mf = 0; mf < 2; ++mf) {
#pragma unroll
    for (int df = 0; df < 4; ++df) {
      int col = df * 16 + c;
      int sI = col >> 2, lowc = (col & 3) << 2;
#pragma unroll
      for (int r = 0; r < 4; ++r) {
        int rloc = 4 * g + r;
        *(float*)(ep + rloc * 256 + (((sI ^ rloc) & 15) << 4) + lowc) = accO[mf][df][r];
      }
    }
    int rr = l >> 2, q4 = l & 3;
    f32x4 aa[4];
#pragma unroll
    for (int j = 0; j < 4; ++j) {
      int sj = q4 * 4 + j;
      aa[j] = *(const f32x4*)(ep + rr * 256 + (((sj ^ rr) & 15) << 4));
    }
    bf16x8 o0, o1;
#pragma unroll
    for (int j = 0; j < 4; ++j) { o0[j] = (__bf16)aa[0][j]; o0[4 + j] = (__bf16)aa[1][j]; }
#pragma unroll
    for (int j = 0; j < 4; ++j) { o1[j] = (__bf16)aa[2][j]; o1[4 + j] = (__bf16)aa[3][j]; }
    int q = w * 32 + mf * 16 + rr;
    char* dst = (char*)Obase + (pbase + q) * 128 + q4 * 32;
    *(bf16x8*)dst = o0;
    *(bf16x8*)(dst + 16) = o1;
  }
}

// ---------------- combine: ao = sum(Oi)/sum(li), scatter to [B,N,C] bf16 ----------------

__global__ __launch_bounds__(256) void k_combine(const __bf16* __restrict__ Op01,
                                                 const __bf16* __restrict__ Op23,
                                                 const float* __restrict__ lpart,
                                                 __bf16* __restrict__ ao) {
  int i = blockIdx.x * 256 + threadIdx.x;           // 24*2048*8 threads, 8 bf16 each
  int d8 = i & 7, q = (i >> 3) & 2047, bh = i >> 14;
  int bg = bh / 12, h = bh - bg * 12;
  const size_t SPL = 24ull * 2048 * 64;
  size_t o0 = (((size_t)bh) * 2048 + q) * 64 + d8 * 8;
  bf16x8 a = *(const bf16x8*)(Op01 + o0);
  bf16x8 b = *(const bf16x8*)(Op01 + SPL + o0);
  bf16x8 cc = *(const bf16x8*)(Op23 + o0);
  bf16x8 d = *(const bf16x8*)(Op23 + SPL + o0);
  size_t lq = (size_t)bh * 2048 + q;
  float lsum = lpart[lq] + lpart[24ull * 2048 + lq] +
               lpart[2 * 24ull * 2048 + lq] + lpart[3 * 24ull * 2048 + lq];
  float rl = __builtin_amdgcn_rcpf(lsum);
  bf16x8 o;
#pragma unroll
  for (int j = 0; j < 8; ++j)
    o[j] = (__bf16)(((float)a[j] + (float)b[j] + (float)cc[j] + (float)d[j]) * rl);
  *(bf16x8*)(ao + ((size_t)bg * 2048 + q) * 768 + h * 64 + d8 * 8) = o;
}

// ---------------- proj GEMM: ao[4096][768] @ wprojT + bias -> f32 out ----------------

__global__ __launch_bounds__(256, 3) void k_proj(const __bf16* __restrict__ A,
                                                 const __bf16* __restrict__ BT,
                                                 const float* __restrict__ bias,
                                                 float* __restrict__ out) {
  __shared__ __align__(16) char smem[32768];
  int tid = threadIdx.x, l = tid & 63, w = tid >> 6, wr = w >> 1, wc = w & 1;
  int m0 = blockIdx.y * 128, n0 = blockIdx.x * 128;
  f32x4 acc[4][4] = {};
  gemm_core<24>((const char*)(A + (size_t)m0 * 768), (const char*)(BT + (size_t)n0 * 768),
                smem, tid, l, wr, wc, acc);
#pragma unroll
  for (int nf = 0; nf < 4; ++nf) {
    int cc = n0 + wc * 64 + nf * 16 + (l & 15);
    float bi = bias[cc];
#pragma unroll
    for (int mf = 0; mf < 4; ++mf) {
      int m = m0 + wr * 64 + mf * 16 + ((l >> 4) << 2);
#pragma unroll
      for (int r = 0; r < 4; ++r)
        out[(size_t)(m + r) * 768 + cc] = acc[mf][nf][r] + bi;
    }
  }
}

// ---------------- launch ----------------

extern "C" void kernel_launch(void* const* d_in, const int* in_sizes, int n_in,
                              void* d_out, int out_size, void* d_ws, size_t ws_size,
                              hipStream_t stream) {
  const float* x      = (const float*)d_in[0];
  const float* w_qkv  = (const float*)d_in[1];
  const float* w_proj = (const float*)d_in[2];
  const float* b_proj = (const float*)d_in[3];
  float* out = (float*)d_out;

  char* ws = (char*)d_ws;
  size_t off = 0;
  auto alloc = [&](size_t bytes) {
    char* p = ws + off;
    off += (bytes + 255) & ~(size_t)255;
    return p;
  };
  __bf16* xb     = (__bf16*)alloc(4096ull * 768 * 2);
  __bf16* wqkvT  = (__bf16*)alloc(2304ull * 768 * 2);
  __bf16* wprojT = (__bf16*)alloc(768ull * 768 * 2);
  __bf16* qb     = (__bf16*)alloc(24ull * 2048 * 64 * 2);
  __bf16* kb     = (__bf16*)alloc(24ull * 2048 * 64 * 2);
  __bf16* vT     = (__bf16*)alloc(24ull * 64 * 2048 * 2);
  __bf16* ao     = (__bf16*)alloc(4096ull * 768 * 2);
  __bf16* Op01   = (__bf16*)alloc(2ull * 24 * 2048 * 64 * 2);
  float*  lpart  = (float*)alloc(4ull * 24 * 2048 * 4);
  __bf16* Op23   = (__bf16*)d_out;   // 12.58 MB scratch, exactly out_size; k_proj overwrites after

  k_cast_x<<<1536, 256, 0, stream>>>(x, xb);
  k_transpose_cast<<<dim3(72, 24), dim3(32, 8), 0, stream>>>(w_qkv, wqkvT, 768, 2304);
  k_transpose_cast<<<dim3(24, 24), dim3(32, 8), 0, stream>>>(w_proj, wprojT, 768, 768);
  k_qkv<<<dim3(18, 32), 256, 0, stream>>>(xb, wqkvT, qb, kb, vT);
  k_attn<<<768, 512, 0, stream>>>(qb, kb, vT, Op01, Op23, lpart);
  k_combine<<<1536, 256, 0, stream>>>(Op01, Op23, lpart, ao);
  k_proj<<<dim3(6, 32), 256, 0, stream>>>(ao, wprojT, b_proj, out);
}

// Round 8
// 96.495 us; speedup vs baseline: 2.5092x; 2.5092x over previous
//
#include <hip/hip_runtime.h>

typedef __attribute__((ext_vector_type(4))) float f32x4;
typedef __attribute__((ext_vector_type(8))) __bf16 bf16x8;
typedef __attribute__((ext_vector_type(4))) __bf16 bf16x4;

#define QSCALE (0.125f * 1.4426950408889634f)   // d^-0.5 * log2(e), folded into q

#define WAITV4 do { asm volatile("s_waitcnt vmcnt(4)" ::: "memory"); \
  __builtin_amdgcn_sched_barrier(0); __builtin_amdgcn_s_barrier(); \
  __builtin_amdgcn_sched_barrier(0); } while (0)
#define WAITV0 do { asm volatile("s_waitcnt vmcnt(0)" ::: "memory"); \
  __builtin_amdgcn_sched_barrier(0); __builtin_amdgcn_s_barrier(); \
  __builtin_amdgcn_sched_barrier(0); } while (0)

__device__ __forceinline__ void load_lds16(const void* g, void* l) {
  __builtin_amdgcn_global_load_lds(
      (const __attribute__((address_space(1))) unsigned int*)g,
      (__attribute__((address_space(3))) unsigned int*)l, 16, 0, 0);
}

__device__ __forceinline__ f32x4 mfma16(bf16x8 a, bf16x8 b, f32x4 c) {
  return __builtin_amdgcn_mfma_f32_16x16x32_bf16(a, b, c, 0, 0, 0);
}

__device__ __forceinline__ bf16x8 cat44(bf16x4 a, bf16x4 b) {
  return __builtin_shufflevector(a, b, 0, 1, 2, 3, 4, 5, 6, 7);
}

// ---------------- prep kernels ----------------

__global__ __launch_bounds__(256) void k_cast_x(const float* __restrict__ in,
                                                __bf16* __restrict__ out) {
  int i = blockIdx.x * 256 + threadIdx.x;           // 8 floats per thread
  const f32x4* in4 = (const f32x4*)in;
  f32x4 a = in4[i * 2], b = in4[i * 2 + 1];
  bf16x8 o;
  o[0] = (__bf16)a[0]; o[1] = (__bf16)a[1]; o[2] = (__bf16)a[2]; o[3] = (__bf16)a[3];
  o[4] = (__bf16)b[0]; o[5] = (__bf16)b[1]; o[6] = (__bf16)b[2]; o[7] = (__bf16)b[3];
  *(bf16x8*)(out + (size_t)i * 8) = o;
}

// in [R][C] f32  ->  out [C][R] bf16
__global__ void k_transpose_cast(const float* __restrict__ in, __bf16* __restrict__ out,
                                 int R, int C) {
  __shared__ float t[32][33];
  int c0 = blockIdx.x * 32, r0 = blockIdx.y * 32;
  int tx = threadIdx.x, ty = threadIdx.y;           // 32 x 8
#pragma unroll
  for (int j = 0; j < 32; j += 8)
    t[ty + j][tx] = in[(size_t)(r0 + ty + j) * C + c0 + tx];
  __syncthreads();
#pragma unroll
  for (int j = 0; j < 32; j += 8)
    out[(size_t)(c0 + ty + j) * R + r0 + tx] = (__bf16)t[tx][ty + j];
}

// -------- GEMM core: TRIPLE-buffered + counted vmcnt (128x128 tile, BK=32, NT=24) --------
// smem 48K: As{0,1,2} [0,24K), Bs{0,1,2} [24K,48K). 4 gload_lds per lane per stage.

__device__ __forceinline__ void gemm_core24(const char* aB, const char* bB,
                                            char* smem, int tid, int l,
                                            int wr, int wc, f32x4 (&acc)[4][4]) {
  auto stage = [&](int buf, int kt) {
#pragma unroll
    for (int is = 0; is < 2; ++is) {
      int o = is * 4096 + tid * 16;
      int row = o >> 6, cb = (o >> 4) & 3;
      int src = row * 1536 + (((cb ^ row) & 3) << 4) + kt * 64;
      load_lds16(aB + src, smem + buf * 8192 + o);
      load_lds16(bB + src, smem + 24576 + buf * 8192 + o);
    }
  };
  auto compute = [&](int buf) {
    const __bf16* As = (const __bf16*)(smem + buf * 8192);
    const __bf16* Bs = (const __bf16*)(smem + 24576 + buf * 8192);
    bf16x8 af[4], bfr[4];
#pragma unroll
    for (int mf = 0; mf < 4; ++mf) {
      int row = wr * 64 + mf * 16 + (l & 15);
      af[mf] = *(const bf16x8*)&As[row * 32 + ((((l >> 4) ^ row) & 3) << 3)];
    }
#pragma unroll
    for (int nf = 0; nf < 4; ++nf) {
      int row = wc * 64 + nf * 16 + (l & 15);
      bfr[nf] = *(const bf16x8*)&Bs[row * 32 + ((((l >> 4) ^ row) & 3) << 3)];
    }
    __builtin_amdgcn_s_setprio(1);
#pragma unroll
    for (int mf = 0; mf < 4; ++mf)
#pragma unroll
      for (int nf = 0; nf < 4; ++nf)
        acc[mf][nf] = mfma16(af[mf], bfr[nf], acc[mf][nf]);
    __builtin_amdgcn_s_setprio(0);
  };
  stage(0, 0); stage(1, 1);
#pragma unroll 3
  for (int t = 0; t < 21; ++t) {       // 21 = 3*7, buf indices fold per unrolled copy
    WAITV4;
    stage((t + 2) % 3, t + 2);         // stages 2..22
    compute(t % 3);
  }
  WAITV4; stage(2, 23); compute(0);    // t=21
  WAITV4; compute(1);                  // t=22
  WAITV0; compute(2);                  // t=23
  __syncthreads();
}

// ---------------- QKV GEMM -> q,k,v with coalesced LDS-transposed epilogues ----------------

__global__ __launch_bounds__(256, 3) void k_qkv(const __bf16* __restrict__ A,
                                                const __bf16* __restrict__ BT,
                                                __bf16* __restrict__ qb,
                                                __bf16* __restrict__ kb,
                                                __bf16* __restrict__ vT) {
  __shared__ __align__(16) char smem[49152];
  int tid = threadIdx.x, l = tid & 63, w = tid >> 6, wr = w >> 1, wc = w & 1;
  int g = l >> 4, c = l & 15;
  int m0 = blockIdx.y * 128, n0 = blockIdx.x * 128;
  f32x4 acc[4][4] = {};
  gemm_core24((const char*)(A + (size_t)m0 * 768), (const char*)(BT + (size_t)n0 * 768),
              smem, tid, l, wr, wc, acc);
  int b = m0 >> 11, m0l = m0 & 2047;
  int sel = n0 / 768;
  int rem = n0 - sel * 768;

  if (sel == 2) {
    // build [dd 128][tok 128] bf16 tile (packed b64 writes), then coalesced vT rows
#pragma unroll
    for (int mf = 0; mf < 4; ++mf) {
      int tokb = wr * 64 + mf * 16 + 4 * g;
      int gr = tokb >> 3, low = (g & 1) << 3;
#pragma unroll
      for (int nf = 0; nf < 4; ++nf) {
        int dd = wc * 64 + nf * 16 + c;
        bf16x4 pk;
        pk[0] = (__bf16)acc[mf][nf][0]; pk[1] = (__bf16)acc[mf][nf][1];
        pk[2] = (__bf16)acc[mf][nf][2]; pk[3] = (__bf16)acc[mf][nf][3];
        *(bf16x4*)(smem + dd * 256 + (((gr ^ (dd & 15)) & 15) << 4) + low) = pk;
      }
    }
    __syncthreads();
#pragma unroll
    for (int p = 0; p < 8; ++p) {
      int idx = p * 256 + tid;
      int dd = idx >> 4, t8 = idx & 15;
      bf16x8 v = *(const bf16x8*)(smem + dd * 256 + (((t8 ^ (dd & 15)) & 15) << 4));
      int colg = rem + dd;
      int h = colg >> 6, d = colg & 63;
      *(bf16x8*)(vT + (((size_t)(b * 12 + h)) * 64 + d) * 2048 + m0l + t8 * 8) = v;
    }
  } else {
    // build [tok 128][col 128] bf16 tile, then coalesced q/k rows
    float qs = (sel == 0) ? QSCALE : 1.0f;
#pragma unroll
    for (int mf = 0; mf < 4; ++mf)
#pragma unroll
      for (int nf = 0; nf < 4; ++nf) {
        int col = wc * 64 + nf * 16 + c;
        int grc = col >> 3, lowc = (col & 7) << 1;
#pragma unroll
        for (int r = 0; r < 4; ++r) {
          int tok = wr * 64 + mf * 16 + 4 * g + r;
          *(__bf16*)(smem + tok * 256 + (((grc ^ (tok & 15)) & 15) << 4) + lowc) =
              (__bf16)(acc[mf][nf][r] * qs);
        }
      }
    __syncthreads();
    __bf16* dst0 = (sel == 0) ? qb : kb;
#pragma unroll
    for (int p = 0; p < 8; ++p) {
      int idx = p * 256 + tid;
      int tok = idx >> 4, hh = (idx >> 3) & 1, d8 = idx & 7;
      int gr = hh * 8 + d8;
      bf16x8 v = *(const bf16x8*)(smem + tok * 256 + (((gr ^ (tok & 15)) & 15) << 4));
      int h = (rem >> 6) + hh;
      *(bf16x8*)(dst0 + (((size_t)(b * 12 + h)) * 2048 + m0l + tok) * 64 + d8 * 8) = v;
    }
  }
}

// ------- flash attention: QBLK=128, KVBLK=64, split=2, TRIPLE-buffered K/V + counted vmcnt ---
// smem 48K: K{0,1,2} [0,24K), V{0,1,2} [24K,48K). 16 K-tiles; 4 gload_lds/lane/stage.
// Q (16KB) staged through [0,16K) first. launch_bounds(256,4): cap 128, no spill.

__global__ __launch_bounds__(256, 4) void k_attn(const __bf16* __restrict__ qb,
                                                 const __bf16* __restrict__ kb,
                                                 const __bf16* __restrict__ vT,
                                                 __bf16* __restrict__ Opart,
                                                 float* __restrict__ lpart) {
  __shared__ __align__(16) char smem[49152];
  int tid = threadIdx.x, l = tid & 63, w = tid >> 6;
  int g = l >> 4, c = l & 15;
  // XCD-aware decode: 768 blocks = 8 XCDs x 96
  int phys = blockIdx.x;
  int lid = (phys & 7) * 96 + (phys >> 3);
  int qt = lid & 15;
  int bhsp = lid >> 4;            // 0..47
  int bh = bhsp % 24, sp = bhsp / 24;   // sp 0..1, 1024 keys each

  const char* qbase  = (const char*)qb + ((size_t)bh * 2048 + qt * 128) * 128;
  const char* kbase0 = (const char*)kb + (size_t)bh * 262144 + (size_t)sp * 131072;
  const char* vbase0 = (const char*)vT + (size_t)bh * 262144 + sp * 2048;

  // stage Q tile [128 q][64 d] into [0,16K), lift to registers
#pragma unroll
  for (int is = 0; is < 4; ++is) {
    int o = is * 4096 + tid * 16;
    int row = o >> 7, cb = (o >> 4) & 7;
    load_lds16(qbase + row * 128 + (((cb ^ row) & 7) << 4), smem + o);
  }
  __syncthreads();
  bf16x8 qf[2][2];
#pragma unroll
  for (int qi = 0; qi < 2; ++qi)
#pragma unroll
    for (int ks = 0; ks < 2; ++ks) {
      int q = w * 32 + qi * 16 + c;
      int gg = ks * 4 + g;
      qf[qi][ks] = *(const bf16x8*)(smem + q * 128 + (((gg ^ q) & 7) << 4));
    }
  __syncthreads();       // all Q reads done before K stage overwrites [0,16K)

  auto stageKV = [&](int buf, int t) {         // 8KB K + 8KB V
    const char* kbase = kbase0 + t * 8192;
    const char* vbase = vbase0 + t * 128;
#pragma unroll
    for (int is = 0; is < 2; ++is) {
      int o = is * 4096 + tid * 16;
      int r = o >> 7, cb = (o >> 4) & 7;
      load_lds16(kbase + r * 128 + (((cb ^ r) & 7) << 4), smem + buf * 8192 + o);
      load_lds16(vbase + (size_t)r * 4096 + (((cb ^ r) & 7) << 4),
                 smem + 24576 + buf * 8192 + o);
    }
  };

  float lacc[2] = {0.f, 0.f};
  f32x4 accO[2][4] = {};

  auto compute = [&](int t, int buf) {
    const char* KsB = smem + buf * 8192;
    const char* VsB = smem + 24576 + buf * 8192;
    // S^T = K @ Q^T (zero-seeded; scores in log2 domain via QSCALE)
    f32x4 s[4][2];
#pragma unroll
    for (int kf = 0; kf < 4; ++kf) {
      s[kf][0] = f32x4{0.f, 0.f, 0.f, 0.f};
      s[kf][1] = f32x4{0.f, 0.f, 0.f, 0.f};
    }
    __builtin_amdgcn_s_setprio(1);
#pragma unroll
    for (int ks = 0; ks < 2; ++ks) {
#pragma unroll
      for (int kf = 0; kf < 4; ++kf) {
        int key = kf * 16 + c;
        int gg = ks * 4 + g;
        bf16x8 kfr = *(const bf16x8*)(KsB + key * 128 + (((gg ^ key) & 7) << 4));
        s[kf][0] = mfma16(kfr, qf[0][ks], s[kf][0]);
        s[kf][1] = mfma16(kfr, qf[1][ks], s[kf][1]);
      }
    }
    __builtin_amdgcn_s_setprio(0);

    // p = exp2(s) via raw v_exp_f32; per-lane partial denominator
#pragma unroll
    for (int kf = 0; kf < 4; ++kf)
#pragma unroll
      for (int qi = 0; qi < 2; ++qi)
#pragma unroll
        for (int r = 0; r < 4; ++r) {
          float p = __builtin_amdgcn_exp2f(s[kf][qi][r]);
          s[kf][qi][r] = p;
          lacc[qi] += p;
        }

    // post-softmax task mask: q<4, key<4, off-diagonal -> 0 (numerator only)
    if (sp == 0 && qt == 0 && t == 0 && w == 0 && g == 0 && c < 4) {
#pragma unroll
      for (int r = 0; r < 4; ++r)
        if (r != c) s[0][0][r] = 0.f;
    }

    // pack P to bf16: pkv[qi][kf] = keys {16*kf + 4g + 0..3} for q-col c
    bf16x4 pkv[2][4];
#pragma unroll
    for (int qi = 0; qi < 2; ++qi)
#pragma unroll
      for (int kf = 0; kf < 4; ++kf) {
        bf16x4 pk;
        pk[0] = (__bf16)s[kf][qi][0]; pk[1] = (__bf16)s[kf][qi][1];
        pk[2] = (__bf16)s[kf][qi][2]; pk[3] = (__bf16)s[kf][qi][3];
        pkv[qi][kf] = pk;
      }

    // PV permuted-k: call ks covers keys {32ks+4g+r} u {32ks+16+4g+r}
    __builtin_amdgcn_s_setprio(1);
#pragma unroll
    for (int ks = 0; ks < 2; ++ks) {
      bf16x8 pa0 = cat44(pkv[0][2 * ks], pkv[0][2 * ks + 1]);
      bf16x8 pa1 = cat44(pkv[1][2 * ks], pkv[1][2 * ks + 1]);
      int low = (g & 1) << 3;
      int vc0 = ks * 4 + (g >> 1);
#pragma unroll
      for (int df = 0; df < 4; ++df) {
        int dd = df * 16 + c;
        const char* vrow = VsB + dd * 128;
        bf16x4 v0 = *(const bf16x4*)(vrow + (((vc0 ^ dd) & 7) << 4) + low);
        bf16x4 v1 = *(const bf16x4*)(vrow + ((((vc0 + 2) ^ dd) & 7) << 4) + low);
        bf16x8 vb = cat44(v0, v1);
        accO[0][df] = mfma16(pa0, vb, accO[0][df]);
        accO[1][df] = mfma16(pa1, vb, accO[1][df]);
      }
    }
    __builtin_amdgcn_s_setprio(0);
  };

  stageKV(0, 0); stageKV(1, 1);
#pragma unroll 3
  for (int t = 0; t < 12; ++t) {       // buf indices fold per unrolled copy
    WAITV4;
    stageKV((t + 2) % 3, t + 2);       // stages 2..13
    compute(t, t % 3);
  }
  WAITV4; stageKV(2, 14); compute(12, 0);
  WAITV4; stageKV(0, 15); compute(13, 1);
  WAITV4; compute(14, 2);
  WAITV0; compute(15, 0);
  __syncthreads();

  // l reduction + store
  size_t pbase = ((size_t)sp * 24 + bh) * 2048 + qt * 128;
  float lfull[2];
#pragma unroll
  for (int qi = 0; qi < 2; ++qi) {
    float rr = lacc[qi];
    rr += __shfl_xor(rr, 16, 64);
    rr += __shfl_xor(rr, 32, 64);
    lfull[qi] = rr;
  }
  if (g == 0) {
#pragma unroll
    for (int qi = 0; qi < 2; ++qi)
      lpart[pbase + w * 32 + qi * 16 + c] = lfull[qi];
  }

  // epilogue: per-wave [16][64] f32 transpose (4KB), 2 passes -> coalesced bf16x8 stores
  char* ep = smem + w * 4096;
#pragma unroll
  for (int mf = 0; mf < 2; ++mf) {
#pragma unroll
    for (int df = 0; df < 4; ++df) {
      int col = df * 16 + c;
      int sI = col >> 2, lowc = (col & 3) << 2;
#pragma unroll
      for (int r = 0; r < 4; ++r) {
        int rloc = 4 * g + r;
        *(float*)(ep + rloc * 256 + (((sI ^ rloc) & 15) << 4) + lowc) = accO[mf][df][r];
      }
    }
    asm volatile("s_waitcnt lgkmcnt(0)" ::: "memory");
    int rr = l >> 2, q4 = l & 3;
    f32x4 aa[4];
#pragma unroll
    for (int j = 0; j < 4; ++j) {
      int sj = q4 * 4 + j;
      aa[j] = *(const f32x4*)(ep + rr * 256 + (((sj ^ rr) & 15) << 4));
    }
    bf16x8 o0, o1;
#pragma unroll
    for (int j = 0; j < 4; ++j) { o0[j] = (__bf16)aa[0][j]; o0[4 + j] = (__bf16)aa[1][j]; }
#pragma unroll
    for (int j = 0; j < 4; ++j) { o1[j] = (__bf16)aa[2][j]; o1[4 + j] = (__bf16)aa[3][j]; }
    int q = w * 32 + mf * 16 + rr;
    char* dst = (char*)Opart + (pbase + q) * 128 + q4 * 32;
    *(bf16x8*)dst = o0;
    *(bf16x8*)(dst + 16) = o1;
  }
}

// ---------------- combine: ao = (O0+O1)/(l0+l1), scatter to [B,N,C] bf16 ----------------

__global__ __launch_bounds__(256) void k_combine(const __bf16* __restrict__ Opart,
                                                 const float* __restrict__ lpart,
                                                 __bf16* __restrict__ ao) {
  int i = blockIdx.x * 256 + threadIdx.x;           // 24*2048*8 threads, 8 bf16 each
  int d8 = i & 7, q = (i >> 3) & 2047, bh = i >> 14;
  int bg = bh / 12, h = bh - bg * 12;
  const size_t SPL = 24ull * 2048 * 64;
  size_t o0 = (((size_t)bh) * 2048 + q) * 64 + d8 * 8;
  bf16x8 a = *(const bf16x8*)(Opart + o0);
  bf16x8 b = *(const bf16x8*)(Opart + SPL + o0);
  size_t lq = (size_t)bh * 2048 + q;
  float lsum = lpart[lq] + lpart[24ull * 2048 + lq];
  float rl = __builtin_amdgcn_rcpf(lsum);
  bf16x8 o;
#pragma unroll
  for (int j = 0; j < 8; ++j)
    o[j] = (__bf16)(((float)a[j] + (float)b[j]) * rl);
  *(bf16x8*)(ao + ((size_t)bg * 2048 + q) * 768 + h * 64 + d8 * 8) = o;
}

// ---------------- proj GEMM: ao[4096][768] @ wprojT + bias -> f32 out ----------------

__global__ __launch_bounds__(256, 3) void k_proj(const __bf16* __restrict__ A,
                                                 const __bf16* __restrict__ BT,
                                                 const float* __restrict__ bias,
                                                 float* __restrict__ out) {
  __shared__ __align__(16) char smem[49152];
  int tid = threadIdx.x, l = tid & 63, w = tid >> 6, wr = w >> 1, wc = w & 1;
  int m0 = blockIdx.y * 128, n0 = blockIdx.x * 128;
  f32x4 acc[4][4] = {};
  gemm_core24((const char*)(A + (size_t)m0 * 768), (const char*)(BT + (size_t)n0 * 768),
              smem, tid, l, wr, wc, acc);
#pragma unroll
  for (int nf = 0; nf < 4; ++nf) {
    int cc = n0 + wc * 64 + nf * 16 + (l & 15);
    float bi = bias[cc];
#pragma unroll
    for (int mf = 0; mf < 4; ++mf) {
      int m = m0 + wr * 64 + mf * 16 + ((l >> 4) << 2);
#pragma unroll
      for (int r = 0; r < 4; ++r)
        out[(size_t)(m + r) * 768 + cc] = acc[mf][nf][r] + bi;
    }
  }
}

// ---------------- launch ----------------

extern "C" void kernel_launch(void* const* d_in, const int* in_sizes, int n_in,
                              void* d_out, int out_size, void* d_ws, size_t ws_size,
                              hipStream_t stream) {
  const float* x      = (const float*)d_in[0];
  const float* w_qkv  = (const float*)d_in[1];
  const float* w_proj = (const float*)d_in[2];
  const float* b_proj = (const float*)d_in[3];
  float* out = (float*)d_out;

  char* ws = (char*)d_ws;
  size_t off = 0;
  auto alloc = [&](size_t bytes) {
    char* p = ws + off;
    off += (bytes + 255) & ~(size_t)255;
    return p;
  };
  __bf16* xb     = (__bf16*)alloc(4096ull * 768 * 2);
  __bf16* wqkvT  = (__bf16*)alloc(2304ull * 768 * 2);
  __bf16* wprojT = (__bf16*)alloc(768ull * 768 * 2);
  __bf16* qb     = (__bf16*)alloc(24ull * 2048 * 64 * 2);
  __bf16* kb     = (__bf16*)alloc(24ull * 2048 * 64 * 2);
  __bf16* vT     = (__bf16*)alloc(24ull * 64 * 2048 * 2);
  __bf16* ao     = (__bf16*)alloc(4096ull * 768 * 2);
  __bf16* Opart  = (__bf16*)alloc(2ull * 24 * 2048 * 64 * 2);
  float*  lpart  = (float*)alloc(2ull * 24 * 2048 * 4);

  k_cast_x<<<1536, 256, 0, stream>>>(x, xb);
  k_transpose_cast<<<dim3(72, 24), dim3(32, 8), 0, stream>>>(w_qkv, wqkvT, 768, 2304);
  k_transpose_cast<<<dim3(24, 24), dim3(32, 8), 0, stream>>>(w_proj, wprojT, 768, 768);
  k_qkv<<<dim3(18, 32), 256, 0, stream>>>(xb, wqkvT, qb, kb, vT);
  k_attn<<<768, 256, 0, stream>>>(qb, kb, vT, Opart, lpart);
  k_combine<<<1536, 256, 0, stream>>>(Opart, lpart, ao);
  k_proj<<<dim3(6, 32), 256, 0, stream>>>(ao, wprojT, b_proj, out);
}

// Round 9
// 93.233 us; speedup vs baseline: 2.5970x; 1.0350x over previous
//
#include <hip/hip_runtime.h>

typedef __attribute__((ext_vector_type(4))) float f32x4;
typedef __attribute__((ext_vector_type(8))) __bf16 bf16x8;
typedef __attribute__((ext_vector_type(4))) __bf16 bf16x4;

#define QSCALE (0.125f * 1.4426950408889634f)   // d^-0.5 * log2(e), folded into q

#define WAITV4 do { asm volatile("s_waitcnt vmcnt(4)" ::: "memory"); \
  __builtin_amdgcn_sched_barrier(0); __builtin_amdgcn_s_barrier(); \
  __builtin_amdgcn_sched_barrier(0); } while (0)
#define WAITV0 do { asm volatile("s_waitcnt vmcnt(0)" ::: "memory"); \
  __builtin_amdgcn_sched_barrier(0); __builtin_amdgcn_s_barrier(); \
  __builtin_amdgcn_sched_barrier(0); } while (0)

__device__ __forceinline__ void load_lds16(const void* g, void* l) {
  __builtin_amdgcn_global_load_lds(
      (const __attribute__((address_space(1))) unsigned int*)g,
      (__attribute__((address_space(3))) unsigned int*)l, 16, 0, 0);
}

__device__ __forceinline__ f32x4 mfma16(bf16x8 a, bf16x8 b, f32x4 c) {
  return __builtin_amdgcn_mfma_f32_16x16x32_bf16(a, b, c, 0, 0, 0);
}

__device__ __forceinline__ bf16x8 cat44(bf16x4 a, bf16x4 b) {
  return __builtin_shufflevector(a, b, 0, 1, 2, 3, 4, 5, 6, 7);
}

// ---------------- prep kernels ----------------

__global__ __launch_bounds__(256) void k_cast_x(const float* __restrict__ in,
                                                __bf16* __restrict__ out) {
  int i = blockIdx.x * 256 + threadIdx.x;           // 8 floats per thread
  const f32x4* in4 = (const f32x4*)in;
  f32x4 a = in4[i * 2], b = in4[i * 2 + 1];
  bf16x8 o;
  o[0] = (__bf16)a[0]; o[1] = (__bf16)a[1]; o[2] = (__bf16)a[2]; o[3] = (__bf16)a[3];
  o[4] = (__bf16)b[0]; o[5] = (__bf16)b[1]; o[6] = (__bf16)b[2]; o[7] = (__bf16)b[3];
  *(bf16x8*)(out + (size_t)i * 8) = o;
}

// in [R][C] f32  ->  out [C][R] bf16
__global__ void k_transpose_cast(const float* __restrict__ in, __bf16* __restrict__ out,
                                 int R, int C) {
  __shared__ float t[32][33];
  int c0 = blockIdx.x * 32, r0 = blockIdx.y * 32;
  int tx = threadIdx.x, ty = threadIdx.y;           // 32 x 8
#pragma unroll
  for (int j = 0; j < 32; j += 8)
    t[ty + j][tx] = in[(size_t)(r0 + ty + j) * C + c0 + tx];
  __syncthreads();
#pragma unroll
  for (int j = 0; j < 32; j += 8)
    out[(size_t)(c0 + ty + j) * R + r0 + tx] = (__bf16)t[tx][ty + j];
}

// -------- GEMM core: TRIPLE-buffered + counted vmcnt (128x128 tile, BK=32, NT=24) --------
// smem 48K: As{0,1,2} [0,24K), Bs{0,1,2} [24K,48K). 4 gload_lds per lane per stage.

__device__ __forceinline__ void gemm_core24(const char* aB, const char* bB,
                                            char* smem, int tid, int l,
                                            int wr, int wc, f32x4 (&acc)[4][4]) {
  auto stage = [&](int buf, int kt) {
#pragma unroll
    for (int is = 0; is < 2; ++is) {
      int o = is * 4096 + tid * 16;
      int row = o >> 6, cb = (o >> 4) & 3;
      int src = row * 1536 + (((cb ^ row) & 3) << 4) + kt * 64;
      load_lds16(aB + src, smem + buf * 8192 + o);
      load_lds16(bB + src, smem + 24576 + buf * 8192 + o);
    }
  };
  auto compute = [&](int buf) {
    const __bf16* As = (const __bf16*)(smem + buf * 8192);
    const __bf16* Bs = (const __bf16*)(smem + 24576 + buf * 8192);
    bf16x8 af[4], bfr[4];
#pragma unroll
    for (int mf = 0; mf < 4; ++mf) {
      int row = wr * 64 + mf * 16 + (l & 15);
      af[mf] = *(const bf16x8*)&As[row * 32 + ((((l >> 4) ^ row) & 3) << 3)];
    }
#pragma unroll
    for (int nf = 0; nf < 4; ++nf) {
      int row = wc * 64 + nf * 16 + (l & 15);
      bfr[nf] = *(const bf16x8*)&Bs[row * 32 + ((((l >> 4) ^ row) & 3) << 3)];
    }
    __builtin_amdgcn_s_setprio(1);
#pragma unroll
    for (int mf = 0; mf < 4; ++mf)
#pragma unroll
      for (int nf = 0; nf < 4; ++nf)
        acc[mf][nf] = mfma16(af[mf], bfr[nf], acc[mf][nf]);
    __builtin_amdgcn_s_setprio(0);
  };
  stage(0, 0); stage(1, 1);
#pragma unroll 3
  for (int t = 0; t < 21; ++t) {       // 21 = 3*7, buf indices fold per unrolled copy
    WAITV4;
    stage((t + 2) % 3, t + 2);         // stages 2..22
    compute(t % 3);
  }
  WAITV4; stage(2, 23); compute(0);    // t=21
  WAITV4; compute(1);                  // t=22
  WAITV0; compute(2);                  // t=23
  __syncthreads();
}

// ---------------- QKV GEMM -> q,k,v with coalesced LDS-transposed epilogues ----------------

__global__ __launch_bounds__(256, 3) void k_qkv(const __bf16* __restrict__ A,
                                                const __bf16* __restrict__ BT,
                                                __bf16* __restrict__ qb,
                                                __bf16* __restrict__ kb,
                                                __bf16* __restrict__ vT) {
  __shared__ __align__(16) char smem[49152];
  int tid = threadIdx.x, l = tid & 63, w = tid >> 6, wr = w >> 1, wc = w & 1;
  int g = l >> 4, c = l & 15;
  int m0 = blockIdx.y * 128, n0 = blockIdx.x * 128;
  f32x4 acc[4][4] = {};
  gemm_core24((const char*)(A + (size_t)m0 * 768), (const char*)(BT + (size_t)n0 * 768),
              smem, tid, l, wr, wc, acc);
  int b = m0 >> 11, m0l = m0 & 2047;
  int sel = n0 / 768;
  int rem = n0 - sel * 768;

  if (sel == 2) {
    // build [dd 128][tok 128] bf16 tile (packed b64 writes), then coalesced vT rows
#pragma unroll
    for (int mf = 0; mf < 4; ++mf) {
      int tokb = wr * 64 + mf * 16 + 4 * g;
      int gr = tokb >> 3, low = (g & 1) << 3;
#pragma unroll
      for (int nf = 0; nf < 4; ++nf) {
        int dd = wc * 64 + nf * 16 + c;
        bf16x4 pk;
        pk[0] = (__bf16)acc[mf][nf][0]; pk[1] = (__bf16)acc[mf][nf][1];
        pk[2] = (__bf16)acc[mf][nf][2]; pk[3] = (__bf16)acc[mf][nf][3];
        *(bf16x4*)(smem + dd * 256 + (((gr ^ (dd & 15)) & 15) << 4) + low) = pk;
      }
    }
    __syncthreads();
#pragma unroll
    for (int p = 0; p < 8; ++p) {
      int idx = p * 256 + tid;
      int dd = idx >> 4, t8 = idx & 15;
      bf16x8 v = *(const bf16x8*)(smem + dd * 256 + (((t8 ^ (dd & 15)) & 15) << 4));
      int colg = rem + dd;
      int h = colg >> 6, d = colg & 63;
      *(bf16x8*)(vT + (((size_t)(b * 12 + h)) * 64 + d) * 2048 + m0l + t8 * 8) = v;
    }
  } else {
    // build [tok 128][col 128] bf16 tile, then coalesced q/k rows
    float qs = (sel == 0) ? QSCALE : 1.0f;
#pragma unroll
    for (int mf = 0; mf < 4; ++mf)
#pragma unroll
      for (int nf = 0; nf < 4; ++nf) {
        int col = wc * 64 + nf * 16 + c;
        int grc = col >> 3, lowc = (col & 7) << 1;
#pragma unroll
        for (int r = 0; r < 4; ++r) {
          int tok = wr * 64 + mf * 16 + 4 * g + r;
          *(__bf16*)(smem + tok * 256 + (((grc ^ (tok & 15)) & 15) << 4) + lowc) =
              (__bf16)(acc[mf][nf][r] * qs);
        }
      }
    __syncthreads();
    __bf16* dst0 = (sel == 0) ? qb : kb;
#pragma unroll
    for (int p = 0; p < 8; ++p) {
      int idx = p * 256 + tid;
      int tok = idx >> 4, hh = (idx >> 3) & 1, d8 = idx & 7;
      int gr = hh * 8 + d8;
      bf16x8 v = *(const bf16x8*)(smem + tok * 256 + (((gr ^ (tok & 15)) & 15) << 4));
      int h = (rem >> 6) + hh;
      *(bf16x8*)(dst0 + (((size_t)(b * 12 + h)) * 2048 + m0l + tok) * 64 + d8 * 8) = v;
    }
  }
}

// ------- flash attention: QBLK=128, KVBLK=64, split=2, triple-buffered K/V + counted vmcnt,
// kf-granular software-pipelined tile body (QK(kf) || exp/pack(kf-1) || PV when ready) -------

__global__ __launch_bounds__(256, 4) void k_attn(const __bf16* __restrict__ qb,
                                                 const __bf16* __restrict__ kb,
                                                 const __bf16* __restrict__ vT,
                                                 __bf16* __restrict__ Opart,
                                                 float* __restrict__ lpart) {
  __shared__ __align__(16) char smem[49152];
  int tid = threadIdx.x, l = tid & 63, w = tid >> 6;
  int g = l >> 4, c = l & 15;
  // XCD-aware decode: 768 blocks = 8 XCDs x 96
  int phys = blockIdx.x;
  int lid = (phys & 7) * 96 + (phys >> 3);
  int qt = lid & 15;
  int bhsp = lid >> 4;            // 0..47
  int bh = bhsp % 24, sp = bhsp / 24;   // sp 0..1, 1024 keys each

  const char* qbase  = (const char*)qb + ((size_t)bh * 2048 + qt * 128) * 128;
  const char* kbase0 = (const char*)kb + (size_t)bh * 262144 + (size_t)sp * 131072;
  const char* vbase0 = (const char*)vT + (size_t)bh * 262144 + sp * 2048;

  // stage Q tile [128 q][64 d] into [0,16K), lift to registers
#pragma unroll
  for (int is = 0; is < 4; ++is) {
    int o = is * 4096 + tid * 16;
    int row = o >> 7, cb = (o >> 4) & 7;
    load_lds16(qbase + row * 128 + (((cb ^ row) & 7) << 4), smem + o);
  }
  __syncthreads();
  bf16x8 qf[2][2];
#pragma unroll
  for (int qi = 0; qi < 2; ++qi)
#pragma unroll
    for (int ks = 0; ks < 2; ++ks) {
      int q = w * 32 + qi * 16 + c;
      int gg = ks * 4 + g;
      qf[qi][ks] = *(const bf16x8*)(smem + q * 128 + (((gg ^ q) & 7) << 4));
    }
  __syncthreads();       // all Q reads done before K stage overwrites [0,16K)

  auto stageKV = [&](int buf, int t) {         // 8KB K + 8KB V
    const char* kbase = kbase0 + t * 8192;
    const char* vbase = vbase0 + t * 128;
#pragma unroll
    for (int is = 0; is < 2; ++is) {
      int o = is * 4096 + tid * 16;
      int r = o >> 7, cb = (o >> 4) & 7;
      load_lds16(kbase + r * 128 + (((cb ^ r) & 7) << 4), smem + buf * 8192 + o);
      load_lds16(vbase + (size_t)r * 4096 + (((cb ^ r) & 7) << 4),
                 smem + 24576 + buf * 8192 + o);
    }
  };

  f32x4 lacc4[2] = {};              // vector partial denominators (4 chains each)
  f32x4 accO[2][4] = {};

  auto compute = [&](int t, int buf) {
    const char* KsB = smem + buf * 8192;
    const char* VsB = smem + 24576 + buf * 8192;
    const f32x4 z = {0.f, 0.f, 0.f, 0.f};
    f32x4 s[4][2];
    bf16x4 pkv[2][4];

    // QK^T for one kf (4 MFMAs, s[kf] complete afterward)
    auto qk = [&](int kf) {
      int key = kf * 16 + c;
      const char* row = KsB + key * 128;
      bf16x8 k0 = *(const bf16x8*)(row + (((g ^ key) & 7) << 4));          // ks=0
      bf16x8 k1 = *(const bf16x8*)(row + ((((4 + g) ^ key) & 7) << 4));    // ks=1
      __builtin_amdgcn_s_setprio(1);
      s[kf][0] = mfma16(k0, qf[0][0], z);
      s[kf][1] = mfma16(k0, qf[1][0], z);
      s[kf][0] = mfma16(k1, qf[0][1], s[kf][0]);
      s[kf][1] = mfma16(k1, qf[1][1], s[kf][1]);
      __builtin_amdgcn_s_setprio(0);
    };
    // softmax numerator + bf16 pack for one kf (16 exp2)
    auto sm = [&](int kf) {
      f32x4 p0, p1;
#pragma unroll
      for (int r = 0; r < 4; ++r) {
        p0[r] = __builtin_amdgcn_exp2f(s[kf][0][r]);
        p1[r] = __builtin_amdgcn_exp2f(s[kf][1][r]);
      }
      if (kf == 0 && sp == 0 && qt == 0 && t == 0 && w == 0 && g == 0 && c < 4) {
#pragma unroll
        for (int r = 0; r < 4; ++r)
          if (r != c) p0[r] = 0.f;     // post-softmax task mask (numerator only)
      }
      lacc4[0] += p0;
      lacc4[1] += p1;
      bf16x4 a, b;
#pragma unroll
      for (int r = 0; r < 4; ++r) { a[r] = (__bf16)p0[r]; b[r] = (__bf16)p1[r]; }
      pkv[0][kf] = a;
      pkv[1][kf] = b;
    };
    // PV for one ks2 (8 MFMAs; needs pkv[*][2ks2], [2ks2+1])
    auto pv = [&](int ks2) {
      bf16x8 pa0 = cat44(pkv[0][2 * ks2], pkv[0][2 * ks2 + 1]);
      bf16x8 pa1 = cat44(pkv[1][2 * ks2], pkv[1][2 * ks2 + 1]);
      int low = (g & 1) << 3;
      int vc0 = ks2 * 4 + (g >> 1);
      __builtin_amdgcn_s_setprio(1);
#pragma unroll
      for (int df = 0; df < 4; ++df) {
        int dd = df * 16 + c;
        const char* vrow = VsB + dd * 128;
        bf16x4 v0 = *(const bf16x4*)(vrow + (((vc0 ^ dd) & 7) << 4) + low);
        bf16x4 v1 = *(const bf16x4*)(vrow + ((((vc0 + 2) ^ dd) & 7) << 4) + low);
        bf16x8 vb = cat44(v0, v1);
        accO[0][df] = mfma16(pa0, vb, accO[0][df]);
        accO[1][df] = mfma16(pa1, vb, accO[1][df]);
      }
      __builtin_amdgcn_s_setprio(0);
    };

    // software-pipelined emission: MFMA groups interleaved with exp/pack VALU
    qk(0); qk(1);
    sm(0);
    qk(2);
    sm(1);
    pv(0);
    qk(3);
    sm(2);
    sm(3);
    pv(1);
  };

  stageKV(0, 0); stageKV(1, 1);
#pragma unroll 3
  for (int t = 0; t < 12; ++t) {       // buf indices fold per unrolled copy
    WAITV4;
    stageKV((t + 2) % 3, t + 2);       // stages 2..13
    compute(t, t % 3);
  }
  WAITV4; stageKV(2, 14); compute(12, 0);
  WAITV4; stageKV(0, 15); compute(13, 1);
  WAITV4; compute(14, 2);
  WAITV0; compute(15, 0);
  __syncthreads();

  // l reduction + store
  size_t pbase = ((size_t)sp * 24 + bh) * 2048 + qt * 128;
  float lfull[2];
#pragma unroll
  for (int qi = 0; qi < 2; ++qi) {
    float rr = lacc4[qi][0] + lacc4[qi][1] + lacc4[qi][2] + lacc4[qi][3];
    rr += __shfl_xor(rr, 16, 64);
    rr += __shfl_xor(rr, 32, 64);
    lfull[qi] = rr;
  }
  if (g == 0) {
#pragma unroll
    for (int qi = 0; qi < 2; ++qi)
      lpart[pbase + w * 32 + qi * 16 + c] = lfull[qi];
  }

  // epilogue: per-wave [16][64] f32 transpose (4KB), 2 passes -> coalesced bf16x8 stores
  char* ep = smem + w * 4096;
#pragma unroll
  for (int mf = 0; mf < 2; ++mf) {
#pragma unroll
    for (int df = 0; df < 4; ++df) {
      int col = df * 16 + c;
      int sI = col >> 2, lowc = (col & 3) << 2;
#pragma unroll
      for (int r = 0; r < 4; ++r) {
        int rloc = 4 * g + r;
        *(float*)(ep + rloc * 256 + (((sI ^ rloc) & 15) << 4) + lowc) = accO[mf][df][r];
      }
    }
    asm volatile("s_waitcnt lgkmcnt(0)" ::: "memory");
    int rr = l >> 2, q4 = l & 3;
    f32x4 aa[4];
#pragma unroll
    for (int j = 0; j < 4; ++j) {
      int sj = q4 * 4 + j;
      aa[j] = *(const f32x4*)(ep + rr * 256 + (((sj ^ rr) & 15) << 4));
    }
    bf16x8 o0, o1;
#pragma unroll
    for (int j = 0; j < 4; ++j) { o0[j] = (__bf16)aa[0][j]; o0[4 + j] = (__bf16)aa[1][j]; }
#pragma unroll
    for (int j = 0; j < 4; ++j) { o1[j] = (__bf16)aa[2][j]; o1[4 + j] = (__bf16)aa[3][j]; }
    int q = w * 32 + mf * 16 + rr;
    char* dst = (char*)Opart + (pbase + q) * 128 + q4 * 32;
    *(bf16x8*)dst = o0;
    *(bf16x8*)(dst + 16) = o1;
  }
}

// ---------------- combine: ao = (O0+O1)/(l0+l1), scatter to [B,N,C] bf16 ----------------

__global__ __launch_bounds__(256) void k_combine(const __bf16* __restrict__ Opart,
                                                 const float* __restrict__ lpart,
                                                 __bf16* __restrict__ ao) {
  int i = blockIdx.x * 256 + threadIdx.x;           // 24*2048*8 threads, 8 bf16 each
  int d8 = i & 7, q = (i >> 3) & 2047, bh = i >> 14;
  int bg = bh / 12, h = bh - bg * 12;
  const size_t SPL = 24ull * 2048 * 64;
  size_t o0 = (((size_t)bh) * 2048 + q) * 64 + d8 * 8;
  bf16x8 a = *(const bf16x8*)(Opart + o0);
  bf16x8 b = *(const bf16x8*)(Opart + SPL + o0);
  size_t lq = (size_t)bh * 2048 + q;
  float lsum = lpart[lq] + lpart[24ull * 2048 + lq];
  float rl = __builtin_amdgcn_rcpf(lsum);
  bf16x8 o;
#pragma unroll
  for (int j = 0; j < 8; ++j)
    o[j] = (__bf16)(((float)a[j] + (float)b[j]) * rl);
  *(bf16x8*)(ao + ((size_t)bg * 2048 + q) * 768 + h * 64 + d8 * 8) = o;
}

// ---------------- proj GEMM: ao[4096][768] @ wprojT + bias -> f32 out ----------------

__global__ __launch_bounds__(256, 3) void k_proj(const __bf16* __restrict__ A,
                                                 const __bf16* __restrict__ BT,
                                                 const float* __restrict__ bias,
                                                 float* __restrict__ out) {
  __shared__ __align__(16) char smem[49152];
  int tid = threadIdx.x, l = tid & 63, w = tid >> 6, wr = w >> 1, wc = w & 1;
  int m0 = blockIdx.y * 128, n0 = blockIdx.x * 128;
  f32x4 acc[4][4] = {};
  gemm_core24((const char*)(A + (size_t)m0 * 768), (const char*)(BT + (size_t)n0 * 768),
              smem, tid, l, wr, wc, acc);
#pragma unroll
  for (int nf = 0; nf < 4; ++nf) {
    int cc = n0 + wc * 64 + nf * 16 + (l & 15);
    float bi = bias[cc];
#pragma unroll
    for (int mf = 0; mf < 4; ++mf) {
      int m = m0 + wr * 64 + mf * 16 + ((l >> 4) << 2);
#pragma unroll
      for (int r = 0; r < 4; ++r)
        out[(size_t)(m + r) * 768 + cc] = acc[mf][nf][r] + bi;
    }
  }
}

// ---------------- launch ----------------

extern "C" void kernel_launch(void* const* d_in, const int* in_sizes, int n_in,
                              void* d_out, int out_size, void* d_ws, size_t ws_size,
                              hipStream_t stream) {
  const float* x      = (const float*)d_in[0];
  const float* w_qkv  = (const float*)d_in[1];
  const float* w_proj = (const float*)d_in[2];
  const float* b_proj = (const float*)d_in[3];
  float* out = (float*)d_out;

  char* ws = (char*)d_ws;
  size_t off = 0;
  auto alloc = [&](size_t bytes) {
    char* p = ws + off;
    off += (bytes + 255) & ~(size_t)255;
    return p;
  };
  __bf16* xb     = (__bf16*)alloc(4096ull * 768 * 2);
  __bf16* wqkvT  = (__bf16*)alloc(2304ull * 768 * 2);
  __bf16* wprojT = (__bf16*)alloc(768ull * 768 * 2);
  __bf16* qb     = (__bf16*)alloc(24ull * 2048 * 64 * 2);
  __bf16* kb     = (__bf16*)alloc(24ull * 2048 * 64 * 2);
  __bf16* vT     = (__bf16*)alloc(24ull * 64 * 2048 * 2);
  __bf16* ao     = (__bf16*)alloc(4096ull * 768 * 2);
  __bf16* Opart  = (__bf16*)alloc(2ull * 24 * 2048 * 64 * 2);
  float*  lpart  = (float*)alloc(2ull * 24 * 2048 * 4);

  k_cast_x<<<1536, 256, 0, stream>>>(x, xb);
  k_transpose_cast<<<dim3(72, 24), dim3(32, 8), 0, stream>>>(w_qkv, wqkvT, 768, 2304);
  k_transpose_cast<<<dim3(24, 24), dim3(32, 8), 0, stream>>>(w_proj, wprojT, 768, 768);
  k_qkv<<<dim3(18, 32), 256, 0, stream>>>(xb, wqkvT, qb, kb, vT);
  k_attn<<<768, 256, 0, stream>>>(qb, kb, vT, Opart, lpart);
  k_combine<<<1536, 256, 0, stream>>>(Opart, lpart, ao);
  k_proj<<<dim3(6, 32), 256, 0, stream>>>(ao, wprojT, b_proj, out);
}

// Round 10
// 91.407 us; speedup vs baseline: 2.6488x; 1.0200x over previous
//
#include <hip/hip_runtime.h>

typedef __attribute__((ext_vector_type(4))) float f32x4;
typedef __attribute__((ext_vector_type(8))) __bf16 bf16x8;
typedef __attribute__((ext_vector_type(4))) __bf16 bf16x4;

#define QSCALE (0.125f * 1.4426950408889634f)   // d^-0.5 * log2(e), folded into q

// counted-vmcnt barrier: asm "memory" blocks mem-op motion from below; the single
// post-barrier sched_barrier keeps LDS reads from floating above s_barrier
// (clang does not treat raw s_barrier as a memory fence).
#define WAITV4 do { asm volatile("s_waitcnt vmcnt(4)" ::: "memory"); \
  __builtin_amdgcn_s_barrier(); __builtin_amdgcn_sched_barrier(0); } while (0)
#define WAITV0 do { asm volatile("s_waitcnt vmcnt(0)" ::: "memory"); \
  __builtin_amdgcn_s_barrier(); __builtin_amdgcn_sched_barrier(0); } while (0)

__device__ __forceinline__ void load_lds16(const void* g, void* l) {
  __builtin_amdgcn_global_load_lds(
      (const __attribute__((address_space(1))) unsigned int*)g,
      (__attribute__((address_space(3))) unsigned int*)l, 16, 0, 0);
}

__device__ __forceinline__ f32x4 mfma16(bf16x8 a, bf16x8 b, f32x4 c) {
  return __builtin_amdgcn_mfma_f32_16x16x32_bf16(a, b, c, 0, 0, 0);
}

__device__ __forceinline__ bf16x8 cat44(bf16x4 a, bf16x4 b) {
  return __builtin_shufflevector(a, b, 0, 1, 2, 3, 4, 5, 6, 7);
}

// ---------------- prep kernels ----------------

__global__ __launch_bounds__(256) void k_cast_x(const float* __restrict__ in,
                                                __bf16* __restrict__ out) {
  int i = blockIdx.x * 256 + threadIdx.x;           // 8 floats per thread
  const f32x4* in4 = (const f32x4*)in;
  f32x4 a = in4[i * 2], b = in4[i * 2 + 1];
  bf16x8 o;
  o[0] = (__bf16)a[0]; o[1] = (__bf16)a[1]; o[2] = (__bf16)a[2]; o[3] = (__bf16)a[3];
  o[4] = (__bf16)b[0]; o[5] = (__bf16)b[1]; o[6] = (__bf16)b[2]; o[7] = (__bf16)b[3];
  *(bf16x8*)(out + (size_t)i * 8) = o;
}

// both weight transposes in one launch: z=0 -> w_qkv [768][2304], z=1 -> w_proj [768][768]
__global__ void k_transpose_cast2(const float* __restrict__ wqkv, __bf16* __restrict__ oq,
                                  const float* __restrict__ wproj, __bf16* __restrict__ op) {
  int z = blockIdx.z;
  if (z == 1 && blockIdx.x >= 24) return;           // uniform per-block exit
  const float* in = z ? wproj : wqkv;
  __bf16* out = z ? op : oq;
  int C = z ? 768 : 2304;
  __shared__ float t[32][33];
  int c0 = blockIdx.x * 32, r0 = blockIdx.y * 32;
  int tx = threadIdx.x, ty = threadIdx.y;           // 32 x 8
#pragma unroll
  for (int j = 0; j < 32; j += 8)
    t[ty + j][tx] = in[(size_t)(r0 + ty + j) * C + c0 + tx];
  __syncthreads();
#pragma unroll
  for (int j = 0; j < 32; j += 8)
    out[(size_t)(c0 + ty + j) * 768 + r0 + tx] = (__bf16)t[tx][ty + j];
}

// -------- GEMM core: TRIPLE-buffered + counted vmcnt (128x128 tile, BK=32, NT=24) --------
// smem 48K: As{0,1,2} [0,24K), Bs{0,1,2} [24K,48K). 4 gload_lds per lane per stage.

__device__ __forceinline__ void gemm_core24(const char* aB, const char* bB,
                                            char* smem, int tid, int l,
                                            int wr, int wc, f32x4 (&acc)[4][4]) {
  auto stage = [&](int buf, int kt) {
#pragma unroll
    for (int is = 0; is < 2; ++is) {
      int o = is * 4096 + tid * 16;
      int row = o >> 6, cb = (o >> 4) & 3;
      int src = row * 1536 + (((cb ^ row) & 3) << 4) + kt * 64;
      load_lds16(aB + src, smem + buf * 8192 + o);
      load_lds16(bB + src, smem + 24576 + buf * 8192 + o);
    }
  };
  auto compute = [&](int buf) {
    const __bf16* As = (const __bf16*)(smem + buf * 8192);
    const __bf16* Bs = (const __bf16*)(smem + 24576 + buf * 8192);
    bf16x8 af[4], bfr[4];
#pragma unroll
    for (int mf = 0; mf < 4; ++mf) {
      int row = wr * 64 + mf * 16 + (l & 15);
      af[mf] = *(const bf16x8*)&As[row * 32 + ((((l >> 4) ^ row) & 3) << 3)];
    }
#pragma unroll
    for (int nf = 0; nf < 4; ++nf) {
      int row = wc * 64 + nf * 16 + (l & 15);
      bfr[nf] = *(const bf16x8*)&Bs[row * 32 + ((((l >> 4) ^ row) & 3) << 3)];
    }
    __builtin_amdgcn_s_setprio(1);
#pragma unroll
    for (int mf = 0; mf < 4; ++mf)
#pragma unroll
      for (int nf = 0; nf < 4; ++nf)
        acc[mf][nf] = mfma16(af[mf], bfr[nf], acc[mf][nf]);
    __builtin_amdgcn_s_setprio(0);
  };
  stage(0, 0); stage(1, 1);
#pragma unroll 3
  for (int t = 0; t < 21; ++t) {       // 21 = 3*7, buf indices fold per unrolled copy
    WAITV4;
    stage((t + 2) % 3, t + 2);         // stages 2..22
    compute(t % 3);
  }
  WAITV4; stage(2, 23); compute(0);    // t=21
  WAITV4; compute(1);                  // t=22
  WAITV0; compute(2);                  // t=23
  __syncthreads();
}

// ---------------- QKV GEMM -> q,k,v with coalesced LDS-transposed epilogues ----------------

__global__ __launch_bounds__(256, 3) void k_qkv(const __bf16* __restrict__ A,
                                                const __bf16* __restrict__ BT,
                                                __bf16* __restrict__ qb,
                                                __bf16* __restrict__ kb,
                                                __bf16* __restrict__ vT) {
  __shared__ __align__(16) char smem[49152];
  int tid = threadIdx.x, l = tid & 63, w = tid >> 6, wr = w >> 1, wc = w & 1;
  int g = l >> 4, c = l & 15;
  int m0 = blockIdx.y * 128, n0 = blockIdx.x * 128;
  f32x4 acc[4][4] = {};
  gemm_core24((const char*)(A + (size_t)m0 * 768), (const char*)(BT + (size_t)n0 * 768),
              smem, tid, l, wr, wc, acc);
  int b = m0 >> 11, m0l = m0 & 2047;
  int sel = n0 / 768;
  int rem = n0 - sel * 768;

  if (sel == 2) {
    // build [dd 128][tok 128] bf16 tile (packed b64 writes), then coalesced vT rows
#pragma unroll
    for (int mf = 0; mf < 4; ++mf) {
      int tokb = wr * 64 + mf * 16 + 4 * g;
      int gr = tokb >> 3, low = (g & 1) << 3;
#pragma unroll
      for (int nf = 0; nf < 4; ++nf) {
        int dd = wc * 64 + nf * 16 + c;
        bf16x4 pk;
        pk[0] = (__bf16)acc[mf][nf][0]; pk[1] = (__bf16)acc[mf][nf][1];
        pk[2] = (__bf16)acc[mf][nf][2]; pk[3] = (__bf16)acc[mf][nf][3];
        *(bf16x4*)(smem + dd * 256 + (((gr ^ (dd & 15)) & 15) << 4) + low) = pk;
      }
    }
    __syncthreads();
#pragma unroll
    for (int p = 0; p < 8; ++p) {
      int idx = p * 256 + tid;
      int dd = idx >> 4, t8 = idx & 15;
      bf16x8 v = *(const bf16x8*)(smem + dd * 256 + (((t8 ^ (dd & 15)) & 15) << 4));
      int colg = rem + dd;
      int h = colg >> 6, d = colg & 63;
      *(bf16x8*)(vT + (((size_t)(b * 12 + h)) * 64 + d) * 2048 + m0l + t8 * 8) = v;
    }
  } else {
    // build [tok 128][col 128] bf16 tile, then coalesced q/k rows
    float qs = (sel == 0) ? QSCALE : 1.0f;
#pragma unroll
    for (int mf = 0; mf < 4; ++mf)
#pragma unroll
      for (int nf = 0; nf < 4; ++nf) {
        int col = wc * 64 + nf * 16 + c;
        int grc = col >> 3, lowc = (col & 7) << 1;
#pragma unroll
        for (int r = 0; r < 4; ++r) {
          int tok = wr * 64 + mf * 16 + 4 * g + r;
          *(__bf16*)(smem + tok * 256 + (((grc ^ (tok & 15)) & 15) << 4) + lowc) =
              (__bf16)(acc[mf][nf][r] * qs);
        }
      }
    __syncthreads();
    __bf16* dst0 = (sel == 0) ? qb : kb;
#pragma unroll
    for (int p = 0; p < 8; ++p) {
      int idx = p * 256 + tid;
      int tok = idx >> 4, hh = (idx >> 3) & 1, d8 = idx & 7;
      int gr = hh * 8 + d8;
      bf16x8 v = *(const bf16x8*)(smem + tok * 256 + (((gr ^ (tok & 15)) & 15) << 4));
      int h = (rem >> 6) + hh;
      *(bf16x8*)(dst0 + (((size_t)(b * 12 + h)) * 2048 + m0l + tok) * 64 + d8 * 8) = v;
    }
  }
}

// ------- flash attention: QBLK=128, KVBLK=64, split=2, triple-buffered K/V + counted vmcnt,
// kf-pipelined body; all swizzled LDS offsets hoisted to lane constants (base + imm reads) ----

__global__ __launch_bounds__(256, 4) void k_attn(const __bf16* __restrict__ qb,
                                                 const __bf16* __restrict__ kb,
                                                 const __bf16* __restrict__ vT,
                                                 __bf16* __restrict__ Opart,
                                                 float* __restrict__ lpart) {
  __shared__ __align__(16) char smem[49152];
  int tid = threadIdx.x, l = tid & 63, w = tid >> 6;
  int g = l >> 4, c = l & 15;
  // XCD-aware decode: 768 blocks = 8 XCDs x 96
  int phys = blockIdx.x;
  int lid = (phys & 7) * 96 + (phys >> 3);
  int qt = lid & 15;
  int bhsp = lid >> 4;            // 0..47
  int bh = bhsp % 24, sp = bhsp / 24;   // sp 0..1, 1024 keys each

  const char* qbase  = (const char*)qb + ((size_t)bh * 2048 + qt * 128) * 128;
  const char* kbase0 = (const char*)kb + (size_t)bh * 262144 + (size_t)sp * 131072;
  const char* vbase0 = (const char*)vT + (size_t)bh * 262144 + sp * 2048;

  // stage Q tile [128 q][64 d] into [0,16K), lift to registers
#pragma unroll
  for (int is = 0; is < 4; ++is) {
    int o = is * 4096 + tid * 16;
    int row = o >> 7, cb = (o >> 4) & 7;
    load_lds16(qbase + row * 128 + (((cb ^ row) & 7) << 4), smem + o);
  }
  __syncthreads();
  bf16x8 qf[2][2];
#pragma unroll
  for (int qi = 0; qi < 2; ++qi)
#pragma unroll
    for (int ks = 0; ks < 2; ++ks) {
      int q = w * 32 + qi * 16 + c;
      int gg = ks * 4 + g;
      qf[qi][ks] = *(const bf16x8*)(smem + q * 128 + (((gg ^ q) & 7) << 4));
    }
  __syncthreads();       // all Q reads done before K stage overwrites [0,16K)

  // lane-constant swizzled offsets (key&7 == c&7 makes XOR term kf/df-invariant)
  int low = (g & 1) << 3;
  int qkoff0 = c * 128 + (((g ^ c) & 7) << 4);            // ks=0, + kf*2048
  int qkoff1 = c * 128 + ((((4 + g) ^ c) & 7) << 4);      // ks=1, + kf*2048
  int vA0 = c * 128 + ((((g >> 1) ^ c) & 7) << 4) + low;        // ks2=0 lo, + df*2048
  int vB0 = c * 128 + ((((2 + (g >> 1)) ^ c) & 7) << 4) + low;  // ks2=0 hi
  int vA1 = c * 128 + ((((4 + (g >> 1)) ^ c) & 7) << 4) + low;  // ks2=1 lo
  int vB1 = c * 128 + ((((6 + (g >> 1)) ^ c) & 7) << 4) + low;  // ks2=1 hi

  auto stageKV = [&](int buf, int t) {         // 8KB K + 8KB V
    const char* kbase = kbase0 + t * 8192;
    const char* vbase = vbase0 + t * 128;
#pragma unroll
    for (int is = 0; is < 2; ++is) {
      int o = is * 4096 + tid * 16;
      int r = o >> 7, cb = (o >> 4) & 7;
      load_lds16(kbase + r * 128 + (((cb ^ r) & 7) << 4), smem + buf * 8192 + o);
      load_lds16(vbase + (size_t)r * 4096 + (((cb ^ r) & 7) << 4),
                 smem + 24576 + buf * 8192 + o);
    }
  };

  f32x4 lacc4[2] = {};              // vector partial denominators (4 chains each)
  f32x4 accO[2][4] = {};

  auto compute = [&](int t, int buf) {
    const char* kq0 = smem + buf * 8192 + qkoff0;
    const char* kq1 = smem + buf * 8192 + qkoff1;
    const char* VsB = smem + 24576 + buf * 8192;
    const f32x4 z = {0.f, 0.f, 0.f, 0.f};
    f32x4 s[4][2];
    bf16x4 pkv[2][4];

    auto qk = [&](int kf) {                    // 4 MFMAs; s[kf] complete afterward
      bf16x8 k0 = *(const bf16x8*)(kq0 + kf * 2048);
      bf16x8 k1 = *(const bf16x8*)(kq1 + kf * 2048);
      __builtin_amdgcn_s_setprio(1);
      s[kf][0] = mfma16(k0, qf[0][0], z);
      s[kf][1] = mfma16(k0, qf[1][0], z);
      s[kf][0] = mfma16(k1, qf[0][1], s[kf][0]);
      s[kf][1] = mfma16(k1, qf[1][1], s[kf][1]);
      __builtin_amdgcn_s_setprio(0);
    };
    auto sm = [&](int kf) {                    // 8 exp2 + pack for one kf
      f32x4 p0, p1;
#pragma unroll
      for (int r = 0; r < 4; ++r) {
        p0[r] = __builtin_amdgcn_exp2f(s[kf][0][r]);
        p1[r] = __builtin_amdgcn_exp2f(s[kf][1][r]);
      }
      if (kf == 0 && sp == 0 && qt == 0 && t == 0 && w == 0 && g == 0 && c < 4) {
#pragma unroll
        for (int r = 0; r < 4; ++r)
          if (r != c) p0[r] = 0.f;             // post-softmax task mask (numerator only)
      }
      lacc4[0] += p0;
      lacc4[1] += p1;
      bf16x4 a, b;
#pragma unroll
      for (int r = 0; r < 4; ++r) { a[r] = (__bf16)p0[r]; b[r] = (__bf16)p1[r]; }
      pkv[0][kf] = a;
      pkv[1][kf] = b;
    };
    auto pv = [&](int ks2) {                   // 8 MFMAs
      bf16x8 pa0 = cat44(pkv[0][2 * ks2], pkv[0][2 * ks2 + 1]);
      bf16x8 pa1 = cat44(pkv[1][2 * ks2], pkv[1][2 * ks2 + 1]);
      const char* p0 = VsB + (ks2 ? vA1 : vA0);
      const char* p1 = VsB + (ks2 ? vB1 : vB0);
      __builtin_amdgcn_s_setprio(1);
#pragma unroll
      for (int df = 0; df < 4; ++df) {
        bf16x4 v0 = *(const bf16x4*)(p0 + df * 2048);
        bf16x4 v1 = *(const bf16x4*)(p1 + df * 2048);
        bf16x8 vb = cat44(v0, v1);
        accO[0][df] = mfma16(pa0, vb, accO[0][df]);
        accO[1][df] = mfma16(pa1, vb, accO[1][df]);
      }
      __builtin_amdgcn_s_setprio(0);
    };

    // software-pipelined emission: MFMA groups interleaved with exp/pack VALU
    qk(0); qk(1);
    sm(0);
    qk(2);
    sm(1);
    pv(0);
    qk(3);
    sm(2);
    sm(3);
    pv(1);
  };

  stageKV(0, 0); stageKV(1, 1);
#pragma unroll 3
  for (int t = 0; t < 12; ++t) {       // buf indices fold per unrolled copy
    WAITV4;
    stageKV((t + 2) % 3, t + 2);       // stages 2..13
    compute(t, t % 3);
  }
  WAITV4; stageKV(2, 14); compute(12, 0);
  WAITV4; stageKV(0, 15); compute(13, 1);
  WAITV4; compute(14, 2);
  WAITV0; compute(15, 0);
  __syncthreads();

  // l reduction + store
  size_t pbase = ((size_t)sp * 24 + bh) * 2048 + qt * 128;
  float lfull[2];
#pragma unroll
  for (int qi = 0; qi < 2; ++qi) {
    float rr = lacc4[qi][0] + lacc4[qi][1] + lacc4[qi][2] + lacc4[qi][3];
    rr += __shfl_xor(rr, 16, 64);
    rr += __shfl_xor(rr, 32, 64);
    lfull[qi] = rr;
  }
  if (g == 0) {
#pragma unroll
    for (int qi = 0; qi < 2; ++qi)
      lpart[pbase + w * 32 + qi * 16 + c] = lfull[qi];
  }

  // epilogue: per-wave [16][64] f32 transpose (4KB), 2 passes -> coalesced bf16x8 stores
  char* ep = smem + w * 4096;
#pragma unroll
  for (int mf = 0; mf < 2; ++mf) {
#pragma unroll
    for (int df = 0; df < 4; ++df) {
      int col = df * 16 + c;
      int sI = col >> 2, lowc = (col & 3) << 2;
#pragma unroll
      for (int r = 0; r < 4; ++r) {
        int rloc = 4 * g + r;
        *(float*)(ep + rloc * 256 + (((sI ^ rloc) & 15) << 4) + lowc) = accO[mf][df][r];
      }
    }
    asm volatile("s_waitcnt lgkmcnt(0)" ::: "memory");
    int rr = l >> 2, q4 = l & 3;
    f32x4 aa[4];
#pragma unroll
    for (int j = 0; j < 4; ++j) {
      int sj = q4 * 4 + j;
      aa[j] = *(const f32x4*)(ep + rr * 256 + (((sj ^ rr) & 15) << 4));
    }
    bf16x8 o0, o1;
#pragma unroll
    for (int j = 0; j < 4; ++j) { o0[j] = (__bf16)aa[0][j]; o0[4 + j] = (__bf16)aa[1][j]; }
#pragma unroll
    for (int j = 0; j < 4; ++j) { o1[j] = (__bf16)aa[2][j]; o1[4 + j] = (__bf16)aa[3][j]; }
    int q = w * 32 + mf * 16 + rr;
    char* dst = (char*)Opart + (pbase + q) * 128 + q4 * 32;
    *(bf16x8*)dst = o0;
    *(bf16x8*)(dst + 16) = o1;
  }
}

// ---------------- combine: ao = (O0+O1)/(l0+l1), scatter to [B,N,C] bf16 ----------------

__global__ __launch_bounds__(256) void k_combine(const __bf16* __restrict__ Opart,
                                                 const float* __restrict__ lpart,
                                                 __bf16* __restrict__ ao) {
  int i = blockIdx.x * 256 + threadIdx.x;           // 24*2048*8 threads, 8 bf16 each
  int d8 = i & 7, q = (i >> 3) & 2047, bh = i >> 14;
  int bg = bh / 12, h = bh - bg * 12;
  const size_t SPL = 24ull * 2048 * 64;
  size_t o0 = (((size_t)bh) * 2048 + q) * 64 + d8 * 8;
  bf16x8 a = *(const bf16x8*)(Opart + o0);
  bf16x8 b = *(const bf16x8*)(Opart + SPL + o0);
  size_t lq = (size_t)bh * 2048 + q;
  float lsum = lpart[lq] + lpart[24ull * 2048 + lq];
  float rl = __builtin_amdgcn_rcpf(lsum);
  bf16x8 o;
#pragma unroll
  for (int j = 0; j < 8; ++j)
    o[j] = (__bf16)(((float)a[j] + (float)b[j]) * rl);
  *(bf16x8*)(ao + ((size_t)bg * 2048 + q) * 768 + h * 64 + d8 * 8) = o;
}

// ---------------- proj GEMM: ao[4096][768] @ wprojT + bias -> f32 out ----------------

__global__ __launch_bounds__(256, 3) void k_proj(const __bf16* __restrict__ A,
                                                 const __bf16* __restrict__ BT,
                                                 const float* __restrict__ bias,
                                                 float* __restrict__ out) {
  __shared__ __align__(16) char smem[49152];
  int tid = threadIdx.x, l = tid & 63, w = tid >> 6, wr = w >> 1, wc = w & 1;
  int m0 = blockIdx.y * 128, n0 = blockIdx.x * 128;
  f32x4 acc[4][4] = {};
  gemm_core24((const char*)(A + (size_t)m0 * 768), (const char*)(BT + (size_t)n0 * 768),
              smem, tid, l, wr, wc, acc);
#pragma unroll
  for (int nf = 0; nf < 4; ++nf) {
    int cc = n0 + wc * 64 + nf * 16 + (l & 15);
    float bi = bias[cc];
#pragma unroll
    for (int mf = 0; mf < 4; ++mf) {
      int m = m0 + wr * 64 + mf * 16 + ((l >> 4) << 2);
#pragma unroll
      for (int r = 0; r < 4; ++r)
        out[(size_t)(m + r) * 768 + cc] = acc[mf][nf][r] + bi;
    }
  }
}

// ---------------- launch ----------------

extern "C" void kernel_launch(void* const* d_in, const int* in_sizes, int n_in,
                              void* d_out, int out_size, void* d_ws, size_t ws_size,
                              hipStream_t stream) {
  const float* x      = (const float*)d_in[0];
  const float* w_qkv  = (const float*)d_in[1];
  const float* w_proj = (const float*)d_in[2];
  const float* b_proj = (const float*)d_in[3];
  float* out = (float*)d_out;

  char* ws = (char*)d_ws;
  size_t off = 0;
  auto alloc = [&](size_t bytes) {
    char* p = ws + off;
    off += (bytes + 255) & ~(size_t)255;
    return p;
  };
  __bf16* xb     = (__bf16*)alloc(4096ull * 768 * 2);
  __bf16* wqkvT  = (__bf16*)alloc(2304ull * 768 * 2);
  __bf16* wprojT = (__bf16*)alloc(768ull * 768 * 2);
  __bf16* qb     = (__bf16*)alloc(24ull * 2048 * 64 * 2);
  __bf16* kb     = (__bf16*)alloc(24ull * 2048 * 64 * 2);
  __bf16* vT     = (__bf16*)alloc(24ull * 64 * 2048 * 2);
  __bf16* ao     = (__bf16*)alloc(4096ull * 768 * 2);
  __bf16* Opart  = (__bf16*)alloc(2ull * 24 * 2048 * 64 * 2);
  float*  lpart  = (float*)alloc(2ull * 24 * 2048 * 4);

  k_cast_x<<<1536, 256, 0, stream>>>(x, xb);
  k_transpose_cast2<<<dim3(72, 24, 2), dim3(32, 8), 0, stream>>>(w_qkv, wqkvT, w_proj, wprojT);
  k_qkv<<<dim3(18, 32), 256, 0, stream>>>(xb, wqkvT, qb, kb, vT);
  k_attn<<<768, 256, 0, stream>>>(qb, kb, vT, Opart, lpart);
  k_combine<<<1536, 256, 0, stream>>>(Opart, lpart, ao);
  k_proj<<<dim3(6, 32), 256, 0, stream>>>(ao, wprojT, b_proj, out);
}